// Round 7
// baseline (649.184 us; speedup 1.0000x reference)
//
#include <hip/hip_runtime.h>
#include <math.h>

#define N_NODES 50000
#define N_EDGES 800000
#define NFEAT 512
#define NHID 256
#define NCODE 64
#define NCLASS 40
#define NCLS_PAD 48

typedef __attribute__((ext_vector_type(8))) short short8;
typedef __attribute__((ext_vector_type(8))) unsigned short ushort8;
typedef __attribute__((ext_vector_type(4))) unsigned short ushort4v;
typedef __attribute__((ext_vector_type(4))) float floatx4;

__device__ inline unsigned short f2bf(float f) {
    unsigned u = __builtin_bit_cast(unsigned, f);
    u += 0x7fff + ((u >> 16) & 1);
    return (unsigned short)(u >> 16);
}
__device__ inline float bf2f(unsigned short h) {
    return __builtin_bit_cast(float, (unsigned)h << 16);
}

// ---------------- CSR build (by dst) ----------------
__global__ __launch_bounds__(256) void hist_kernel(const int* __restrict__ dst,
                                                   int* __restrict__ counts) {
    int t = blockIdx.x * 256 + threadIdx.x;
    if (t < N_EDGES) atomicAdd(&counts[dst[t]], 1);
}

__global__ __launch_bounds__(1024) void scan_kernel(const int* __restrict__ counts,
                                                    int* __restrict__ offsets) {
    __shared__ int sums[1024];
    int t = threadIdx.x;
    const int CH = (N_NODES + 1023) / 1024;  // 49
    int start = t * CH;
    int end = min(start + CH, N_NODES);
    int s = 0;
    for (int i = start; i < end; i++) s += counts[i];
    sums[t] = s;
    __syncthreads();
    for (int off = 1; off < 1024; off <<= 1) {
        int v = (t >= off) ? sums[t - off] : 0;
        __syncthreads();
        sums[t] += v;
        __syncthreads();
    }
    int run = (t == 0) ? 0 : sums[t - 1];
    for (int i = start; i < end; i++) {
        offsets[i] = run;
        run += counts[i];
    }
    if (t == 1023) offsets[N_NODES] = sums[1023];
}

// scatter edges into dst-sorted order as packed (src, w_bits) int2
__global__ __launch_bounds__(256) void scatter_kernel(const int* __restrict__ dst,
                                                      const int* __restrict__ src,
                                                      const float* __restrict__ w,
                                                      const int* __restrict__ offsets,
                                                      int* __restrict__ cursor,
                                                      int2* __restrict__ edges) {
    int t = blockIdx.x * 256 + threadIdx.x;
    if (t < N_EDGES) {
        int d = dst[t];
        int pos = offsets[d] + atomicAdd(&cursor[d], 1);
        edges[pos] = make_int2(src[t], __builtin_bit_cast(int, w[t]));
    }
}

// ---------------- Fused weight prep ----------------
// Bsw1: gemm1 B in MFMA-fragment order [c(16)][nt(16)][lane(64)][j(8)]   = 131072
//       element = W1[k][col], col = nt*16+(lane&15), k = c*32+((lane>>4)&3)*8+j
// Bsw2: gemm2 B same order [c(16)][nt(3)][lane(64)][j(8)]                = 24576
// W_mulvt[128][256] = bf16([W_mu|W_lv]^T)                                = 32768
// W_dect[256][64]   = bf16(W_dec^T)                                      = 16384
__global__ __launch_bounds__(256) void wprep_kernel(const float* __restrict__ W1,
                                                    const float* __restrict__ W2,
                                                    const float* __restrict__ W_mu,
                                                    const float* __restrict__ W_lv,
                                                    const float* __restrict__ W_dec,
                                                    unsigned short* __restrict__ Bsw1,
                                                    unsigned short* __restrict__ Bsw2,
                                                    unsigned short* __restrict__ W_mulvt,
                                                    unsigned short* __restrict__ W_dect) {
    int idx = blockIdx.x * 256 + threadIdx.x;
    if (idx < NFEAT * NHID) {
        int j = idx & 7;
        int l = (idx >> 3) & 63;
        int nt = (idx >> 9) & 15;
        int c = idx >> 13;
        int col = nt * 16 + (l & 15);
        int k = c * 32 + ((l >> 4) & 3) * 8 + j;
        Bsw1[idx] = f2bf(W1[(size_t)k * NHID + col]);
    } else if (idx < NFEAT * NHID + NCLS_PAD * NFEAT) {
        int i2 = idx - NFEAT * NHID;
        int c = i2 / 1536;
        int r = i2 - c * 1536;
        int nt = r >> 9;
        int q = r & 511;
        int l = q >> 3;
        int j = q & 7;
        int col = nt * 16 + (l & 15);
        int k = c * 32 + ((l >> 4) & 3) * 8 + j;
        Bsw2[i2] = (col < NCLASS) ? f2bf(W2[(size_t)k * NCLASS + col]) : (unsigned short)0;
    } else if (idx < NFEAT * NHID + NCLS_PAD * NFEAT + 128 * 256) {
        int i2 = idx - NFEAT * NHID - NCLS_PAD * NFEAT;
        int j = i2 >> 8;
        int k = i2 & 255;
        float v = (j < 64) ? W_mu[(size_t)k * NCODE + j] : W_lv[(size_t)k * NCODE + (j - 64)];
        W_mulvt[i2] = f2bf(v);
    } else if (idx < NFEAT * NHID + NCLS_PAD * NFEAT + 128 * 256 + 256 * 64) {
        int i2 = idx - NFEAT * NHID - NCLS_PAD * NFEAT - 128 * 256;
        int n = i2 >> 6;
        int k = i2 & 63;
        W_dect[i2] = f2bf(W_dec[(size_t)k * NHID + n]);
    }
}

// ---------------- GEMM1 (bf16 MFMA, barrier-free): support1b = bf16(x @ W1) ----------------
// no LDS, no barriers: A-frags direct from global (fp32->bf16 in-reg),
// B-frags from pre-swizzled Bsw1 (L2-resident, 16B/lane coalesced)
__global__ __launch_bounds__(256) void gemm1_mfma(const float* __restrict__ A,
                                                  const unsigned short* __restrict__ Bsw,
                                                  unsigned short* __restrict__ C) {
    int t = threadIdx.x;
    int wave = t >> 6, lane = t & 63;
    int quad = lane >> 4, m16 = lane & 15;
    int m0 = blockIdx.x * 64 + wave * 16;

    int arow = m0 + m16;
    if (arow >= N_NODES) arow = N_NODES - 1;
    const float* Abase = A + (size_t)arow * NFEAT + quad * 8;
    const unsigned short* Bbase = Bsw + lane * 8;

    floatx4 acc[16];
#pragma unroll
    for (int i = 0; i < 16; i++) acc[i] = (floatx4){0.f, 0.f, 0.f, 0.f};

#pragma unroll 2
    for (int c = 0; c < 16; c++) {
        float4 a0 = *(const float4*)(Abase + c * 32);
        float4 a1 = *(const float4*)(Abase + c * 32 + 4);
        ushort8 av;
        av[0] = f2bf(a0.x); av[1] = f2bf(a0.y); av[2] = f2bf(a0.z); av[3] = f2bf(a0.w);
        av[4] = f2bf(a1.x); av[5] = f2bf(a1.y); av[6] = f2bf(a1.z); av[7] = f2bf(a1.w);
        short8 afrag = __builtin_bit_cast(short8, av);
        const unsigned short* bp = Bbase + (size_t)c * 16 * 512;
#pragma unroll
        for (int nt = 0; nt < 16; nt++) {
            short8 bfrag = *(const short8*)(bp + nt * 512);
            acc[nt] = __builtin_amdgcn_mfma_f32_16x16x32_bf16(afrag, bfrag, acc[nt], 0, 0, 0);
        }
    }
#pragma unroll
    for (int nt = 0; nt < 16; nt++) {
        int col = nt * 16 + m16;
#pragma unroll
        for (int r = 0; r < 4; r++) {
            int row = m0 + quad * 4 + r;
            if (row < N_NODES) C[(size_t)row * NHID + col] = f2bf(acc[nt][r]);
        }
    }
}

// ---------------- SpMM1 + bias + relu -> x1cat[:,256:512] (bf16) ----------------
__global__ __launch_bounds__(256) void spmm1_kernel(const int* __restrict__ offsets,
                                                    const int2* __restrict__ edges,
                                                    const unsigned short* __restrict__ S1b,
                                                    const float* __restrict__ b1,
                                                    unsigned short* __restrict__ x1cat) {
    int n = blockIdx.x * 4 + (threadIdx.x >> 6);
    int lane = threadIdx.x & 63;
    int beg = offsets[n], end = offsets[n + 1];
    float ax = 0.f, ay = 0.f, az = 0.f, aw = 0.f;
    int i = beg;
    for (; i + 4 <= end; i += 4) {
        int2 e0 = edges[i], e1 = edges[i + 1], e2 = edges[i + 2], e3 = edges[i + 3];
        float w0 = __builtin_bit_cast(float, e0.y);
        float w1 = __builtin_bit_cast(float, e1.y);
        float w2 = __builtin_bit_cast(float, e2.y);
        float w3 = __builtin_bit_cast(float, e3.y);
        ushort4v r0 = *(const ushort4v*)&S1b[(size_t)e0.x * NHID + lane * 4];
        ushort4v r1 = *(const ushort4v*)&S1b[(size_t)e1.x * NHID + lane * 4];
        ushort4v r2 = *(const ushort4v*)&S1b[(size_t)e2.x * NHID + lane * 4];
        ushort4v r3 = *(const ushort4v*)&S1b[(size_t)e3.x * NHID + lane * 4];
        ax += w0 * bf2f(r0[0]) + w1 * bf2f(r1[0]) + w2 * bf2f(r2[0]) + w3 * bf2f(r3[0]);
        ay += w0 * bf2f(r0[1]) + w1 * bf2f(r1[1]) + w2 * bf2f(r2[1]) + w3 * bf2f(r3[1]);
        az += w0 * bf2f(r0[2]) + w1 * bf2f(r1[2]) + w2 * bf2f(r2[2]) + w3 * bf2f(r3[2]);
        aw += w0 * bf2f(r0[3]) + w1 * bf2f(r1[3]) + w2 * bf2f(r2[3]) + w3 * bf2f(r3[3]);
    }
    for (; i < end; i++) {
        int2 e = edges[i];
        float ww = __builtin_bit_cast(float, e.y);
        ushort4v r = *(const ushort4v*)&S1b[(size_t)e.x * NHID + lane * 4];
        ax += ww * bf2f(r[0]); ay += ww * bf2f(r[1]);
        az += ww * bf2f(r[2]); aw += ww * bf2f(r[3]);
    }
    float4 bb = *(const float4*)&b1[lane * 4];
    ushort4v hb;
    hb[0] = f2bf(fmaxf(ax + bb.x, 0.f));
    hb[1] = f2bf(fmaxf(ay + bb.y, 0.f));
    hb[2] = f2bf(fmaxf(az + bb.z, 0.f));
    hb[3] = f2bf(fmaxf(aw + bb.w, 0.f));
    *(ushort4v*)&x1cat[(size_t)n * (2 * NHID) + NHID + lane * 4] = hb;
}

// ---------------- Fused MLP via MFMA: 16 nodes/block ----------------
__global__ __launch_bounds__(256) void mlp_mfma(const unsigned short* __restrict__ x1cat_ro,
                                                const float* __restrict__ eps,
                                                const float* __restrict__ b_mu,
                                                const float* __restrict__ b_lv,
                                                const unsigned short* __restrict__ W_mulvt,
                                                const float* __restrict__ b_dec,
                                                const unsigned short* __restrict__ W_dect,
                                                unsigned short* __restrict__ x1cat) {
    __shared__ float smulv[16][132];
    __shared__ unsigned short z_bf[16][72];
    int t = threadIdx.x;
    int wave = t >> 6, lane = t & 63;
    int quad = lane >> 4, m16 = lane & 15;
    int node0 = blockIdx.x * 16;

    // ---- phase A: mu||lv = h1 @ W_mulvt ----
    {
        floatx4 acc[2];
        acc[0] = (floatx4){0.f, 0.f, 0.f, 0.f};
        acc[1] = (floatx4){0.f, 0.f, 0.f, 0.f};
        const unsigned short* Abase =
            x1cat_ro + (size_t)(node0 + m16) * 512 + 256 + quad * 8;
        const unsigned short* Bb0 = W_mulvt + (size_t)(wave * 32 + m16) * 256 + quad * 8;
        const unsigned short* Bb1 = Bb0 + 16 * 256;
#pragma unroll
        for (int k0 = 0; k0 < 256; k0 += 32) {
            short8 afrag = *(const short8*)(Abase + k0);
            short8 bf0 = *(const short8*)(Bb0 + k0);
            short8 bf1 = *(const short8*)(Bb1 + k0);
            acc[0] = __builtin_amdgcn_mfma_f32_16x16x32_bf16(afrag, bf0, acc[0], 0, 0, 0);
            acc[1] = __builtin_amdgcn_mfma_f32_16x16x32_bf16(afrag, bf1, acc[1], 0, 0, 0);
        }
#pragma unroll
        for (int nt = 0; nt < 2; nt++) {
            int j = wave * 32 + nt * 16 + m16;
            float bias = (j < 64) ? b_mu[j] : b_lv[j - 64];
#pragma unroll
            for (int r = 0; r < 4; r++)
                smulv[quad * 4 + r][j] = acc[nt][r] + bias;
        }
    }
    __syncthreads();
    // ---- phase B: z = mu + eps*exp(lv) ----
#pragma unroll
    for (int r = 0; r < 4; r++) {
        int idx = t + r * 256;
        int n = idx >> 6, j = idx & 63;
        float z = smulv[n][j] + eps[(size_t)node0 * NCODE + idx] * expf(smulv[n][64 + j]);
        z_bf[n][j] = f2bf(z);
    }
    __syncthreads();
    // ---- phase C: x1 = relu(z @ W_dect + b_dec) ----
    {
        floatx4 acc[4];
#pragma unroll
        for (int i = 0; i < 4; i++) acc[i] = (floatx4){0.f, 0.f, 0.f, 0.f};
#pragma unroll
        for (int ks = 0; ks < 2; ks++) {
            int k0 = ks * 32;
            short8 afrag = *(const short8*)&z_bf[m16][k0 + quad * 8];
#pragma unroll
            for (int nt = 0; nt < 4; nt++) {
                int col = wave * 64 + nt * 16 + m16;
                short8 bfrag = *(const short8*)(W_dect + (size_t)col * 64 + k0 + quad * 8);
                acc[nt] = __builtin_amdgcn_mfma_f32_16x16x32_bf16(afrag, bfrag, acc[nt], 0, 0, 0);
            }
        }
#pragma unroll
        for (int nt = 0; nt < 4; nt++) {
            int col = wave * 64 + nt * 16 + m16;
            float bias = b_dec[col];
#pragma unroll
            for (int r = 0; r < 4; r++) {
                int node = node0 + quad * 4 + r;
                x1cat[(size_t)node * 512 + col] = f2bf(fmaxf(acc[nt][r] + bias, 0.f));
            }
        }
    }
}

// ---------------- GEMM2 (bf16 MFMA, barrier-free): support2 = x1cat @ W2 ----------------
__global__ __launch_bounds__(256) void gemm2_mfma(const unsigned short* __restrict__ Xb,
                                                  const unsigned short* __restrict__ Bsw,
                                                  float* __restrict__ S2) {
    int t = threadIdx.x;
    int wave = t >> 6, lane = t & 63;
    int quad = lane >> 4, m16 = lane & 15;
    int m0 = blockIdx.x * 64 + wave * 16;

    int arow = m0 + m16;
    if (arow >= N_NODES) arow = N_NODES - 1;
    const unsigned short* Abase = Xb + (size_t)arow * NFEAT + quad * 8;
    const unsigned short* Bbase = Bsw + lane * 8;

    floatx4 acc[3];
#pragma unroll
    for (int i = 0; i < 3; i++) acc[i] = (floatx4){0.f, 0.f, 0.f, 0.f};

#pragma unroll 4
    for (int c = 0; c < 16; c++) {
        short8 afrag = *(const short8*)(Abase + c * 32);
        const unsigned short* bp = Bbase + (size_t)c * 3 * 512;
#pragma unroll
        for (int nt = 0; nt < 3; nt++) {
            short8 bfrag = *(const short8*)(bp + nt * 512);
            acc[nt] = __builtin_amdgcn_mfma_f32_16x16x32_bf16(afrag, bfrag, acc[nt], 0, 0, 0);
        }
    }
#pragma unroll
    for (int nt = 0; nt < 3; nt++) {
        int col = nt * 16 + m16;
        if (col < NCLASS) {
#pragma unroll
            for (int r = 0; r < 4; r++) {
                int row = m0 + quad * 4 + r;
                if (row < N_NODES) S2[(size_t)row * NCLASS + col] = acc[nt][r];
            }
        }
    }
}

// ---------------- SpMM2 + bias + log_softmax -> out ----------------
__global__ __launch_bounds__(256) void spmm2_softmax_kernel(const int* __restrict__ offsets,
                                                            const int2* __restrict__ edges,
                                                            const float* __restrict__ S2,
                                                            const float* __restrict__ b2,
                                                            float* __restrict__ out) {
    int wave = threadIdx.x >> 6;
    int lane = threadIdx.x & 63;
    int n = blockIdx.x * 4 + wave;
    int beg = offsets[n], end = offsets[n + 1];
    float acc = 0.f;
    int i = beg;
    for (; i + 2 <= end; i += 2) {
        int2 e0 = edges[i], e1 = edges[i + 1];
        float w0 = __builtin_bit_cast(float, e0.y);
        float w1 = __builtin_bit_cast(float, e1.y);
        if (lane < NCLASS) {
            float v0 = S2[(size_t)e0.x * NCLASS + lane];
            float v1 = S2[(size_t)e1.x * NCLASS + lane];
            acc += w0 * v0 + w1 * v1;
        }
    }
    for (; i < end; i++) {
        int2 e = edges[i];
        float ww = __builtin_bit_cast(float, e.y);
        if (lane < NCLASS) acc += ww * S2[(size_t)e.x * NCLASS + lane];
    }
    float v = (lane < NCLASS) ? (acc + b2[lane]) : -INFINITY;
    float m = v;
#pragma unroll
    for (int off = 32; off > 0; off >>= 1) m = fmaxf(m, __shfl_xor(m, off));
    float ex = (lane < NCLASS) ? expf(v - m) : 0.f;
    float ssum = ex;
#pragma unroll
    for (int off = 32; off > 0; off >>= 1) ssum += __shfl_xor(ssum, off);
    if (lane < NCLASS) out[(size_t)n * NCLASS + lane] = v - m - logf(ssum);
}

extern "C" void kernel_launch(void* const* d_in, const int* in_sizes, int n_in,
                              void* d_out, int out_size, void* d_ws, size_t ws_size,
                              hipStream_t stream) {
    const float* x     = (const float*)d_in[0];
    const int*   esrc  = (const int*)d_in[1];
    const int*   edst  = (const int*)d_in[2];
    const float* ew    = (const float*)d_in[3];
    const float* eps   = (const float*)d_in[4];
    const float* W1    = (const float*)d_in[5];
    const float* b1    = (const float*)d_in[6];
    const float* W_mu  = (const float*)d_in[7];
    const float* b_mu  = (const float*)d_in[8];
    const float* W_lv  = (const float*)d_in[9];
    const float* b_lv  = (const float*)d_in[10];
    const float* W_dec = (const float*)d_in[11];
    const float* b_dec = (const float*)d_in[12];
    const float* W2    = (const float*)d_in[13];
    const float* b2    = (const float*)d_in[14];
    float* out = (float*)d_out;

    // workspace layout (counts & cursor adjacent -> single memset)
    unsigned short* support1b = (unsigned short*)d_ws;                     // 12.8M u16
    unsigned short* x1cat = support1b + (size_t)N_NODES * NHID;            // 25.6M u16
    float* support2 = (float*)(x1cat + (size_t)N_NODES * 2 * NHID);        // 2M f32
    unsigned short* Bsw1   = (unsigned short*)(support2 + (size_t)N_NODES * NCLASS);
    unsigned short* Bsw2   = Bsw1 + (size_t)NHID * NFEAT;
    unsigned short* W_mulvt = Bsw2 + (size_t)NCLS_PAD * NFEAT;
    unsigned short* W_dect  = W_mulvt + 128 * 256;
    int*   counts   = (int*)(W_dect + 256 * 64);
    int*   cursor   = counts + N_NODES;
    int*   offsets  = cursor + N_NODES;     // N+1
    int2*  edges    = (int2*)(offsets + N_NODES + 1);
    edges = (int2*)(((size_t)edges + 7) & ~(size_t)7);
    size_t need = (size_t)((char*)(edges + N_EDGES) - (char*)d_ws);
    if (ws_size < need) return;

    hipMemsetAsync(counts, 0, 2 * N_NODES * sizeof(int), stream);  // counts + cursor
    hist_kernel<<<(N_EDGES + 255) / 256, 256, 0, stream>>>(edst, counts);
    scan_kernel<<<1, 1024, 0, stream>>>(counts, offsets);
    scatter_kernel<<<(N_EDGES + 255) / 256, 256, 0, stream>>>(edst, esrc, ew, offsets, cursor,
                                                              edges);

    wprep_kernel<<<800, 256, 0, stream>>>(W1, W2, W_mu, W_lv, W_dec, Bsw1, Bsw2, W_mulvt, W_dect);
    gemm1_mfma<<<(N_NODES + 63) / 64, 256, 0, stream>>>(x, Bsw1, support1b);
    spmm1_kernel<<<N_NODES / 4, 256, 0, stream>>>(offsets, edges, support1b, b1, x1cat);
    mlp_mfma<<<N_NODES / 16, 256, 0, stream>>>(x1cat, eps, b_mu, b_lv, W_mulvt, b_dec, W_dect,
                                               x1cat);
    gemm2_mfma<<<(N_NODES + 63) / 64, 256, 0, stream>>>(x1cat, Bsw2, support2);
    spmm2_softmax_kernel<<<N_NODES / 4, 256, 0, stream>>>(offsets, edges, support2, b2, out);
}

// Round 8
// 532.370 us; speedup vs baseline: 1.2194x; 1.2194x over previous
//
#include <hip/hip_runtime.h>
#include <math.h>

#define N_NODES 50000
#define N_EDGES 800000
#define NFEAT 512
#define NHID 256
#define NCODE 64
#define NCLASS 40
#define NCLS_PAD 48

typedef __attribute__((ext_vector_type(8))) short short8;
typedef __attribute__((ext_vector_type(8))) unsigned short ushort8;
typedef __attribute__((ext_vector_type(4))) unsigned short ushort4v;
typedef __attribute__((ext_vector_type(4))) float floatx4;

__device__ inline unsigned short f2bf(float f) {
    unsigned u = __builtin_bit_cast(unsigned, f);
    u += 0x7fff + ((u >> 16) & 1);
    return (unsigned short)(u >> 16);
}
__device__ inline float bf2f(unsigned short h) {
    return __builtin_bit_cast(float, (unsigned)h << 16);
}

// ---------------- CSR build (by dst) ----------------
__global__ __launch_bounds__(256) void hist_kernel(const int* __restrict__ dst,
                                                   int* __restrict__ counts) {
    int t = blockIdx.x * 256 + threadIdx.x;
    if (t < N_EDGES) atomicAdd(&counts[dst[t]], 1);
}

__global__ __launch_bounds__(1024) void scan_kernel(const int* __restrict__ counts,
                                                    int* __restrict__ offsets) {
    __shared__ int sums[1024];
    int t = threadIdx.x;
    const int CH = (N_NODES + 1023) / 1024;  // 49
    int start = t * CH;
    int end = min(start + CH, N_NODES);
    int s = 0;
    for (int i = start; i < end; i++) s += counts[i];
    sums[t] = s;
    __syncthreads();
    for (int off = 1; off < 1024; off <<= 1) {
        int v = (t >= off) ? sums[t - off] : 0;
        __syncthreads();
        sums[t] += v;
        __syncthreads();
    }
    int run = (t == 0) ? 0 : sums[t - 1];
    for (int i = start; i < end; i++) {
        offsets[i] = run;
        run += counts[i];
    }
    if (t == 1023) offsets[N_NODES] = sums[1023];
}

// scatter edges into dst-sorted order as packed (src, w_bits) int2
__global__ __launch_bounds__(256) void scatter_kernel(const int* __restrict__ dst,
                                                      const int* __restrict__ src,
                                                      const float* __restrict__ w,
                                                      const int* __restrict__ offsets,
                                                      int* __restrict__ cursor,
                                                      int2* __restrict__ edges) {
    int t = blockIdx.x * 256 + threadIdx.x;
    if (t < N_EDGES) {
        int d = dst[t];
        int pos = offsets[d] + atomicAdd(&cursor[d], 1);
        edges[pos] = make_int2(src[t], __builtin_bit_cast(int, w[t]));
    }
}

// ---------------- Fused weight prep: W1t / W2bt / W_mulvt / W_dect ----------------
__global__ __launch_bounds__(256) void wprep_kernel(const float* __restrict__ W1,
                                                    const float* __restrict__ W2,
                                                    const float* __restrict__ W_mu,
                                                    const float* __restrict__ W_lv,
                                                    const float* __restrict__ W_dec,
                                                    unsigned short* __restrict__ W1t,
                                                    unsigned short* __restrict__ W2bt,
                                                    unsigned short* __restrict__ W_mulvt,
                                                    unsigned short* __restrict__ W_dect) {
    int idx = blockIdx.x * 256 + threadIdx.x;
    if (idx < NFEAT * NHID) {
        int k = idx >> 8;
        int n = idx & 255;
        W1t[(size_t)n * NFEAT + k] = f2bf(W1[idx]);
    } else if (idx < NFEAT * NHID + NCLS_PAD * NFEAT) {
        int i2 = idx - NFEAT * NHID;
        int n = i2 >> 9;
        int k = i2 & 511;
        W2bt[i2] = (n < NCLASS) ? f2bf(W2[(size_t)k * NCLASS + n]) : (unsigned short)0;
    } else if (idx < NFEAT * NHID + NCLS_PAD * NFEAT + 128 * 256) {
        int i2 = idx - NFEAT * NHID - NCLS_PAD * NFEAT;
        int j = i2 >> 8;
        int k = i2 & 255;
        float v = (j < 64) ? W_mu[(size_t)k * NCODE + j] : W_lv[(size_t)k * NCODE + (j - 64)];
        W_mulvt[i2] = f2bf(v);
    } else if (idx < NFEAT * NHID + NCLS_PAD * NFEAT + 128 * 256 + 256 * 64) {
        int i2 = idx - NFEAT * NHID - NCLS_PAD * NFEAT - 128 * 256;
        int n = i2 >> 6;
        int k = i2 & 63;
        W_dect[i2] = f2bf(W_dec[(size_t)k * NHID + n]);
    }
}

// ---------------- GEMM1 (bf16 MFMA, 64x128 tile, LDS-staged): support1b = bf16(x @ W1) --------
// grid (782, 2): block computes rows m0..m0+63, cols n0..n0+127.
// 1564 blocks -> ~6 blocks/CU resident (15.4 KB LDS) to hide the barrier drain.
__global__ __launch_bounds__(256) void gemm1_mfma(const float* __restrict__ A,
                                                  const unsigned short* __restrict__ Bt,
                                                  unsigned short* __restrict__ C) {
    __shared__ unsigned short As[64][40];
    __shared__ unsigned short Bs[128][40];
    int t = threadIdx.x;
    int wave = t >> 6, lane = t & 63;
    int quad = lane >> 4, m16 = lane & 15;
    int m0 = blockIdx.x * 64;
    int n0 = blockIdx.y * 128;

    floatx4 acc[8];
#pragma unroll
    for (int i = 0; i < 8; i++) acc[i] = (floatx4){0.f, 0.f, 0.f, 0.f};

    int ar = t >> 2;            // 0..63 A row
    int ako = (t & 3) * 8;      // k offset
    int arow = m0 + ar;
    if (arow >= N_NODES) arow = N_NODES - 1;
    const float* Abase = A + (size_t)arow * NFEAT + ako;

    int bcol = t >> 1;          // 0..127 local col
    int bko = (t & 1) * 16;     // k half
    const unsigned short* Bbase = Bt + (size_t)(n0 + bcol) * NFEAT + bko;

    for (int k0 = 0; k0 < NFEAT; k0 += 32) {
        float4 a0 = *(const float4*)(Abase + k0);
        float4 a1 = *(const float4*)(Abase + k0 + 4);
        ushort8 b0 = *(const ushort8*)(Bbase + k0);
        ushort8 b1 = *(const ushort8*)(Bbase + k0 + 8);
        __syncthreads();
        ushort8 av;
        av[0] = f2bf(a0.x); av[1] = f2bf(a0.y); av[2] = f2bf(a0.z); av[3] = f2bf(a0.w);
        av[4] = f2bf(a1.x); av[5] = f2bf(a1.y); av[6] = f2bf(a1.z); av[7] = f2bf(a1.w);
        *(ushort8*)&As[ar][ako] = av;
        *(ushort8*)&Bs[bcol][bko] = b0;
        *(ushort8*)&Bs[bcol][bko + 8] = b1;
        __syncthreads();
        short8 afrag = *(const short8*)&As[wave * 16 + m16][quad * 8];
#pragma unroll
        for (int nt = 0; nt < 8; nt++) {
            short8 bfrag = *(const short8*)&Bs[nt * 16 + m16][quad * 8];
            acc[nt] = __builtin_amdgcn_mfma_f32_16x16x32_bf16(afrag, bfrag, acc[nt], 0, 0, 0);
        }
    }
#pragma unroll
    for (int nt = 0; nt < 8; nt++) {
        int col = n0 + nt * 16 + m16;
#pragma unroll
        for (int r = 0; r < 4; r++) {
            int row = m0 + wave * 16 + quad * 4 + r;
            if (row < N_NODES) C[(size_t)row * NHID + col] = f2bf(acc[nt][r]);
        }
    }
}

// ---------------- SpMM1 + bias + relu -> x1cat[:,256:512] (bf16) ----------------
__global__ __launch_bounds__(256) void spmm1_kernel(const int* __restrict__ offsets,
                                                    const int2* __restrict__ edges,
                                                    const unsigned short* __restrict__ S1b,
                                                    const float* __restrict__ b1,
                                                    unsigned short* __restrict__ x1cat) {
    int n = blockIdx.x * 4 + (threadIdx.x >> 6);
    int lane = threadIdx.x & 63;
    int beg = offsets[n], end = offsets[n + 1];
    float ax = 0.f, ay = 0.f, az = 0.f, aw = 0.f;
    int i = beg;
    for (; i + 4 <= end; i += 4) {
        int2 e0 = edges[i], e1 = edges[i + 1], e2 = edges[i + 2], e3 = edges[i + 3];
        float w0 = __builtin_bit_cast(float, e0.y);
        float w1 = __builtin_bit_cast(float, e1.y);
        float w2 = __builtin_bit_cast(float, e2.y);
        float w3 = __builtin_bit_cast(float, e3.y);
        ushort4v r0 = *(const ushort4v*)&S1b[(size_t)e0.x * NHID + lane * 4];
        ushort4v r1 = *(const ushort4v*)&S1b[(size_t)e1.x * NHID + lane * 4];
        ushort4v r2 = *(const ushort4v*)&S1b[(size_t)e2.x * NHID + lane * 4];
        ushort4v r3 = *(const ushort4v*)&S1b[(size_t)e3.x * NHID + lane * 4];
        ax += w0 * bf2f(r0[0]) + w1 * bf2f(r1[0]) + w2 * bf2f(r2[0]) + w3 * bf2f(r3[0]);
        ay += w0 * bf2f(r0[1]) + w1 * bf2f(r1[1]) + w2 * bf2f(r2[1]) + w3 * bf2f(r3[1]);
        az += w0 * bf2f(r0[2]) + w1 * bf2f(r1[2]) + w2 * bf2f(r2[2]) + w3 * bf2f(r3[2]);
        aw += w0 * bf2f(r0[3]) + w1 * bf2f(r1[3]) + w2 * bf2f(r2[3]) + w3 * bf2f(r3[3]);
    }
    for (; i < end; i++) {
        int2 e = edges[i];
        float ww = __builtin_bit_cast(float, e.y);
        ushort4v r = *(const ushort4v*)&S1b[(size_t)e.x * NHID + lane * 4];
        ax += ww * bf2f(r[0]); ay += ww * bf2f(r[1]);
        az += ww * bf2f(r[2]); aw += ww * bf2f(r[3]);
    }
    float4 bb = *(const float4*)&b1[lane * 4];
    ushort4v hb;
    hb[0] = f2bf(fmaxf(ax + bb.x, 0.f));
    hb[1] = f2bf(fmaxf(ay + bb.y, 0.f));
    hb[2] = f2bf(fmaxf(az + bb.z, 0.f));
    hb[3] = f2bf(fmaxf(aw + bb.w, 0.f));
    *(ushort4v*)&x1cat[(size_t)n * (2 * NHID) + NHID + lane * 4] = hb;
}

// ---------------- Fused MLP via MFMA: 16 nodes/block ----------------
__global__ __launch_bounds__(256) void mlp_mfma(const unsigned short* __restrict__ x1cat_ro,
                                                const float* __restrict__ eps,
                                                const float* __restrict__ b_mu,
                                                const float* __restrict__ b_lv,
                                                const unsigned short* __restrict__ W_mulvt,
                                                const float* __restrict__ b_dec,
                                                const unsigned short* __restrict__ W_dect,
                                                unsigned short* __restrict__ x1cat) {
    __shared__ float smulv[16][132];
    __shared__ unsigned short z_bf[16][72];
    int t = threadIdx.x;
    int wave = t >> 6, lane = t & 63;
    int quad = lane >> 4, m16 = lane & 15;
    int node0 = blockIdx.x * 16;

    // ---- phase A: mu||lv = h1 @ W_mulvt ----
    {
        floatx4 acc[2];
        acc[0] = (floatx4){0.f, 0.f, 0.f, 0.f};
        acc[1] = (floatx4){0.f, 0.f, 0.f, 0.f};
        const unsigned short* Abase =
            x1cat_ro + (size_t)(node0 + m16) * 512 + 256 + quad * 8;
        const unsigned short* Bb0 = W_mulvt + (size_t)(wave * 32 + m16) * 256 + quad * 8;
        const unsigned short* Bb1 = Bb0 + 16 * 256;
#pragma unroll
        for (int k0 = 0; k0 < 256; k0 += 32) {
            short8 afrag = *(const short8*)(Abase + k0);
            short8 bf0 = *(const short8*)(Bb0 + k0);
            short8 bf1 = *(const short8*)(Bb1 + k0);
            acc[0] = __builtin_amdgcn_mfma_f32_16x16x32_bf16(afrag, bf0, acc[0], 0, 0, 0);
            acc[1] = __builtin_amdgcn_mfma_f32_16x16x32_bf16(afrag, bf1, acc[1], 0, 0, 0);
        }
#pragma unroll
        for (int nt = 0; nt < 2; nt++) {
            int j = wave * 32 + nt * 16 + m16;
            float bias = (j < 64) ? b_mu[j] : b_lv[j - 64];
#pragma unroll
            for (int r = 0; r < 4; r++)
                smulv[quad * 4 + r][j] = acc[nt][r] + bias;
        }
    }
    __syncthreads();
    // ---- phase B: z = mu + eps*exp(lv) ----
#pragma unroll
    for (int r = 0; r < 4; r++) {
        int idx = t + r * 256;
        int n = idx >> 6, j = idx & 63;
        float z = smulv[n][j] + eps[(size_t)node0 * NCODE + idx] * expf(smulv[n][64 + j]);
        z_bf[n][j] = f2bf(z);
    }
    __syncthreads();
    // ---- phase C: x1 = relu(z @ W_dect + b_dec) ----
    {
        floatx4 acc[4];
#pragma unroll
        for (int i = 0; i < 4; i++) acc[i] = (floatx4){0.f, 0.f, 0.f, 0.f};
#pragma unroll
        for (int ks = 0; ks < 2; ks++) {
            int k0 = ks * 32;
            short8 afrag = *(const short8*)&z_bf[m16][k0 + quad * 8];
#pragma unroll
            for (int nt = 0; nt < 4; nt++) {
                int col = wave * 64 + nt * 16 + m16;
                short8 bfrag = *(const short8*)(W_dect + (size_t)col * 64 + k0 + quad * 8);
                acc[nt] = __builtin_amdgcn_mfma_f32_16x16x32_bf16(afrag, bfrag, acc[nt], 0, 0, 0);
            }
        }
#pragma unroll
        for (int nt = 0; nt < 4; nt++) {
            int col = wave * 64 + nt * 16 + m16;
            float bias = b_dec[col];
#pragma unroll
            for (int r = 0; r < 4; r++) {
                int node = node0 + quad * 4 + r;
                x1cat[(size_t)node * 512 + col] = f2bf(fmaxf(acc[nt][r] + bias, 0.f));
            }
        }
    }
}

// ---------------- GEMM2 (bf16 MFMA, LDS-staged, reg-prefetch): support2 = x1cat @ W2 ----------
__global__ __launch_bounds__(256) void gemm2_mfma(const unsigned short* __restrict__ Xb,
                                                  const unsigned short* __restrict__ Bt,
                                                  float* __restrict__ S2) {
    __shared__ unsigned short As[64][40];
    __shared__ unsigned short Bs[48][40];
    int t = threadIdx.x;
    int wave = t >> 6, lane = t & 63;
    int quad = lane >> 4, m16 = lane & 15;
    int m0 = blockIdx.x * 64;

    floatx4 acc[3];
#pragma unroll
    for (int i = 0; i < 3; i++) acc[i] = (floatx4){0.f, 0.f, 0.f, 0.f};

    int ar = t >> 2;
    int ako = (t & 3) * 8;
    int arow = m0 + ar;
    if (arow >= N_NODES) arow = N_NODES - 1;
    const unsigned short* Abase = Xb + (size_t)arow * NFEAT + ako;
    const unsigned short* Bbase = Bt + (size_t)(t >> 2) * NFEAT + ako;
    bool bload = (t >> 2) < NCLS_PAD;

    ushort8 a0 = *(const ushort8*)(Abase);
    ushort8 b0;
    if (bload) b0 = *(const ushort8*)(Bbase);

    for (int k0 = 0; k0 < NFEAT; k0 += 32) {
        __syncthreads();
        *(ushort8*)&As[ar][ako] = a0;
        if (bload) *(ushort8*)&Bs[t >> 2][ako] = b0;
        __syncthreads();
        int kn = (k0 + 32 < NFEAT) ? (k0 + 32) : k0;
        a0 = *(const ushort8*)(Abase + kn);
        if (bload) b0 = *(const ushort8*)(Bbase + kn);
        short8 afrag = *(const short8*)&As[wave * 16 + m16][quad * 8];
#pragma unroll
        for (int nt = 0; nt < 3; nt++) {
            short8 bfrag = *(const short8*)&Bs[nt * 16 + m16][quad * 8];
            acc[nt] = __builtin_amdgcn_mfma_f32_16x16x32_bf16(afrag, bfrag, acc[nt], 0, 0, 0);
        }
    }
#pragma unroll
    for (int nt = 0; nt < 3; nt++) {
        int col = nt * 16 + m16;
        if (col < NCLASS) {
#pragma unroll
            for (int r = 0; r < 4; r++) {
                int row = m0 + wave * 16 + quad * 4 + r;
                if (row < N_NODES) S2[(size_t)row * NCLASS + col] = acc[nt][r];
            }
        }
    }
}

// ---------------- SpMM2 + bias + log_softmax -> out ----------------
__global__ __launch_bounds__(256) void spmm2_softmax_kernel(const int* __restrict__ offsets,
                                                            const int2* __restrict__ edges,
                                                            const float* __restrict__ S2,
                                                            const float* __restrict__ b2,
                                                            float* __restrict__ out) {
    int wave = threadIdx.x >> 6;
    int lane = threadIdx.x & 63;
    int n = blockIdx.x * 4 + wave;
    int beg = offsets[n], end = offsets[n + 1];
    float acc = 0.f;
    int i = beg;
    for (; i + 4 <= end; i += 4) {
        int2 e0 = edges[i], e1 = edges[i + 1], e2 = edges[i + 2], e3 = edges[i + 3];
        float w0 = __builtin_bit_cast(float, e0.y);
        float w1 = __builtin_bit_cast(float, e1.y);
        float w2 = __builtin_bit_cast(float, e2.y);
        float w3 = __builtin_bit_cast(float, e3.y);
        if (lane < NCLASS) {
            float v0 = S2[(size_t)e0.x * NCLASS + lane];
            float v1 = S2[(size_t)e1.x * NCLASS + lane];
            float v2 = S2[(size_t)e2.x * NCLASS + lane];
            float v3 = S2[(size_t)e3.x * NCLASS + lane];
            acc += w0 * v0 + w1 * v1 + w2 * v2 + w3 * v3;
        }
    }
    for (; i < end; i++) {
        int2 e = edges[i];
        float ww = __builtin_bit_cast(float, e.y);
        if (lane < NCLASS) acc += ww * S2[(size_t)e.x * NCLASS + lane];
    }
    float v = (lane < NCLASS) ? (acc + b2[lane]) : -INFINITY;
    float m = v;
#pragma unroll
    for (int off = 32; off > 0; off >>= 1) m = fmaxf(m, __shfl_xor(m, off));
    float ex = (lane < NCLASS) ? expf(v - m) : 0.f;
    float ssum = ex;
#pragma unroll
    for (int off = 32; off > 0; off >>= 1) ssum += __shfl_xor(ssum, off);
    if (lane < NCLASS) out[(size_t)n * NCLASS + lane] = v - m - logf(ssum);
}

extern "C" void kernel_launch(void* const* d_in, const int* in_sizes, int n_in,
                              void* d_out, int out_size, void* d_ws, size_t ws_size,
                              hipStream_t stream) {
    const float* x     = (const float*)d_in[0];
    const int*   esrc  = (const int*)d_in[1];
    const int*   edst  = (const int*)d_in[2];
    const float* ew    = (const float*)d_in[3];
    const float* eps   = (const float*)d_in[4];
    const float* W1    = (const float*)d_in[5];
    const float* b1    = (const float*)d_in[6];
    const float* W_mu  = (const float*)d_in[7];
    const float* b_mu  = (const float*)d_in[8];
    const float* W_lv  = (const float*)d_in[9];
    const float* b_lv  = (const float*)d_in[10];
    const float* W_dec = (const float*)d_in[11];
    const float* b_dec = (const float*)d_in[12];
    const float* W2    = (const float*)d_in[13];
    const float* b2    = (const float*)d_in[14];
    float* out = (float*)d_out;

    // workspace layout (counts & cursor adjacent -> single memset)
    unsigned short* support1b = (unsigned short*)d_ws;                     // 12.8M u16
    unsigned short* x1cat = support1b + (size_t)N_NODES * NHID;            // 25.6M u16
    float* support2 = (float*)(x1cat + (size_t)N_NODES * 2 * NHID);        // 2M f32
    unsigned short* W1t    = (unsigned short*)(support2 + (size_t)N_NODES * NCLASS);
    unsigned short* W2bt   = W1t + (size_t)NHID * NFEAT;
    unsigned short* W_mulvt = W2bt + (size_t)NCLS_PAD * NFEAT;
    unsigned short* W_dect  = W_mulvt + 128 * 256;
    int*   counts   = (int*)(W_dect + 256 * 64);
    int*   cursor   = counts + N_NODES;
    int*   offsets  = cursor + N_NODES;     // N+1
    int2*  edges    = (int2*)(offsets + N_NODES + 1);
    edges = (int2*)(((size_t)edges + 7) & ~(size_t)7);
    size_t need = (size_t)((char*)(edges + N_EDGES) - (char*)d_ws);
    if (ws_size < need) return;

    hipMemsetAsync(counts, 0, 2 * N_NODES * sizeof(int), stream);  // counts + cursor
    hist_kernel<<<(N_EDGES + 255) / 256, 256, 0, stream>>>(edst, counts);
    scan_kernel<<<1, 1024, 0, stream>>>(counts, offsets);
    scatter_kernel<<<(N_EDGES + 255) / 256, 256, 0, stream>>>(edst, esrc, ew, offsets, cursor,
                                                              edges);

    wprep_kernel<<<800, 256, 0, stream>>>(W1, W2, W_mu, W_lv, W_dec, W1t, W2bt, W_mulvt, W_dect);
    dim3 g1((N_NODES + 63) / 64, 2);
    gemm1_mfma<<<g1, 256, 0, stream>>>(x, W1t, support1b);
    spmm1_kernel<<<N_NODES / 4, 256, 0, stream>>>(offsets, edges, support1b, b1, x1cat);
    mlp_mfma<<<N_NODES / 16, 256, 0, stream>>>(x1cat, eps, b_mu, b_lv, W_mulvt, b_dec, W_dect,
                                               x1cat);
    gemm2_mfma<<<(N_NODES + 63) / 64, 256, 0, stream>>>(x1cat, W2bt, support2);
    spmm2_softmax_kernel<<<N_NODES / 4, 256, 0, stream>>>(offsets, edges, support2, b2, out);
}

// Round 9
// 463.996 us; speedup vs baseline: 1.3991x; 1.1474x over previous
//
#include <hip/hip_runtime.h>
#include <math.h>

#define N_NODES 50000
#define N_EDGES 800000
#define NFEAT 512
#define NHID 256
#define NCODE 64
#define NCLASS 40
#define NCLS_PAD 48
#define NB_SCAN 196  // ceil(50000/256)

typedef __attribute__((ext_vector_type(8))) short short8;
typedef __attribute__((ext_vector_type(8))) unsigned short ushort8;
typedef __attribute__((ext_vector_type(4))) unsigned short ushort4v;
typedef __attribute__((ext_vector_type(4))) float floatx4;

__device__ inline unsigned short f2bf(float f) {
    unsigned u = __builtin_bit_cast(unsigned, f);
    u += 0x7fff + ((u >> 16) & 1);
    return (unsigned short)(u >> 16);
}
__device__ inline float bf2f(unsigned short h) {
    return __builtin_bit_cast(float, (unsigned)h << 16);
}

// ---------------- CSR build (by dst) ----------------
__global__ __launch_bounds__(256) void hist_kernel(const int* __restrict__ dst,
                                                   int* __restrict__ counts) {
    int t = blockIdx.x * 256 + threadIdx.x;
    if (t < N_EDGES) atomicAdd(&counts[dst[t]], 1);
}

// 3-phase device scan (replaces the 77 µs single-block scan)
__global__ __launch_bounds__(256) void scan_block_sums(const int* __restrict__ counts,
                                                       int* __restrict__ blockSums) {
    __shared__ int red[256];
    int t = threadIdx.x;
    int i = blockIdx.x * 256 + t;
    red[t] = (i < N_NODES) ? counts[i] : 0;
    __syncthreads();
#pragma unroll
    for (int off = 128; off > 0; off >>= 1) {
        if (t < off) red[t] += red[t + off];
        __syncthreads();
    }
    if (t == 0) blockSums[blockIdx.x] = red[0];
}

__global__ __launch_bounds__(256) void scan_block_offsets(const int* __restrict__ blockSums,
                                                          int* __restrict__ blockOffsets,
                                                          int* __restrict__ offsets) {
    __shared__ int s[256];
    int t = threadIdx.x;
    int v = (t < NB_SCAN) ? blockSums[t] : 0;
    s[t] = v;
    __syncthreads();
#pragma unroll
    for (int off = 1; off < 256; off <<= 1) {
        int x = (t >= off) ? s[t - off] : 0;
        __syncthreads();
        s[t] += x;
        __syncthreads();
    }
    if (t < NB_SCAN) blockOffsets[t] = s[t] - v;  // exclusive
    if (t == 255) offsets[N_NODES] = s[255];      // total = E
}

__global__ __launch_bounds__(256) void scan_final(const int* __restrict__ counts,
                                                  const int* __restrict__ blockOffsets,
                                                  int* __restrict__ offsets) {
    __shared__ int s[256];
    int t = threadIdx.x;
    int i = blockIdx.x * 256 + t;
    int v = (i < N_NODES) ? counts[i] : 0;
    s[t] = v;
    __syncthreads();
#pragma unroll
    for (int off = 1; off < 256; off <<= 1) {
        int x = (t >= off) ? s[t - off] : 0;
        __syncthreads();
        s[t] += x;
        __syncthreads();
    }
    if (i < N_NODES) offsets[i] = blockOffsets[blockIdx.x] + s[t] - v;  // exclusive
}

// scatter edges into dst-sorted order as packed (src, w_bits) int2
__global__ __launch_bounds__(256) void scatter_kernel(const int* __restrict__ dst,
                                                      const int* __restrict__ src,
                                                      const float* __restrict__ w,
                                                      const int* __restrict__ offsets,
                                                      int* __restrict__ cursor,
                                                      int2* __restrict__ edges) {
    int t = blockIdx.x * 256 + threadIdx.x;
    if (t < N_EDGES) {
        int d = dst[t];
        int pos = offsets[d] + atomicAdd(&cursor[d], 1);
        edges[pos] = make_int2(src[t], __builtin_bit_cast(int, w[t]));
    }
}

// ---------------- Fused weight prep: W1t / W2bt / W_mulvt / W_dect ----------------
__global__ __launch_bounds__(256) void wprep_kernel(const float* __restrict__ W1,
                                                    const float* __restrict__ W2,
                                                    const float* __restrict__ W_mu,
                                                    const float* __restrict__ W_lv,
                                                    const float* __restrict__ W_dec,
                                                    unsigned short* __restrict__ W1t,
                                                    unsigned short* __restrict__ W2bt,
                                                    unsigned short* __restrict__ W_mulvt,
                                                    unsigned short* __restrict__ W_dect) {
    int idx = blockIdx.x * 256 + threadIdx.x;
    if (idx < NFEAT * NHID) {
        int k = idx >> 8;
        int n = idx & 255;
        W1t[(size_t)n * NFEAT + k] = f2bf(W1[idx]);
    } else if (idx < NFEAT * NHID + NCLS_PAD * NFEAT) {
        int i2 = idx - NFEAT * NHID;
        int n = i2 >> 9;
        int k = i2 & 511;
        W2bt[i2] = (n < NCLASS) ? f2bf(W2[(size_t)k * NCLASS + n]) : (unsigned short)0;
    } else if (idx < NFEAT * NHID + NCLS_PAD * NFEAT + 128 * 256) {
        int i2 = idx - NFEAT * NHID - NCLS_PAD * NFEAT;
        int j = i2 >> 8;
        int k = i2 & 255;
        float v = (j < 64) ? W_mu[(size_t)k * NCODE + j] : W_lv[(size_t)k * NCODE + (j - 64)];
        W_mulvt[i2] = f2bf(v);
    } else if (idx < NFEAT * NHID + NCLS_PAD * NFEAT + 128 * 256 + 256 * 64) {
        int i2 = idx - NFEAT * NHID - NCLS_PAD * NFEAT - 128 * 256;
        int n = i2 >> 6;
        int k = i2 & 63;
        W_dect[i2] = f2bf(W_dec[(size_t)k * NHID + n]);
    }
}

// ---------------- GEMM1 (bf16 MFMA, 64x128 tile, LDS-staged): support1b = bf16(x @ W1) --------
__global__ __launch_bounds__(256) void gemm1_mfma(const float* __restrict__ A,
                                                  const unsigned short* __restrict__ Bt,
                                                  unsigned short* __restrict__ C) {
    __shared__ unsigned short As[64][40];
    __shared__ unsigned short Bs[128][40];
    int t = threadIdx.x;
    int wave = t >> 6, lane = t & 63;
    int quad = lane >> 4, m16 = lane & 15;
    int m0 = blockIdx.x * 64;
    int n0 = blockIdx.y * 128;

    floatx4 acc[8];
#pragma unroll
    for (int i = 0; i < 8; i++) acc[i] = (floatx4){0.f, 0.f, 0.f, 0.f};

    int ar = t >> 2;            // 0..63 A row
    int ako = (t & 3) * 8;      // k offset
    int arow = m0 + ar;
    if (arow >= N_NODES) arow = N_NODES - 1;
    const float* Abase = A + (size_t)arow * NFEAT + ako;

    int bcol = t >> 1;          // 0..127 local col
    int bko = (t & 1) * 16;     // k half
    const unsigned short* Bbase = Bt + (size_t)(n0 + bcol) * NFEAT + bko;

    for (int k0 = 0; k0 < NFEAT; k0 += 32) {
        float4 a0 = *(const float4*)(Abase + k0);
        float4 a1 = *(const float4*)(Abase + k0 + 4);
        ushort8 b0 = *(const ushort8*)(Bbase + k0);
        ushort8 b1 = *(const ushort8*)(Bbase + k0 + 8);
        __syncthreads();
        ushort8 av;
        av[0] = f2bf(a0.x); av[1] = f2bf(a0.y); av[2] = f2bf(a0.z); av[3] = f2bf(a0.w);
        av[4] = f2bf(a1.x); av[5] = f2bf(a1.y); av[6] = f2bf(a1.z); av[7] = f2bf(a1.w);
        *(ushort8*)&As[ar][ako] = av;
        *(ushort8*)&Bs[bcol][bko] = b0;
        *(ushort8*)&Bs[bcol][bko + 8] = b1;
        __syncthreads();
        short8 afrag = *(const short8*)&As[wave * 16 + m16][quad * 8];
#pragma unroll
        for (int nt = 0; nt < 8; nt++) {
            short8 bfrag = *(const short8*)&Bs[nt * 16 + m16][quad * 8];
            acc[nt] = __builtin_amdgcn_mfma_f32_16x16x32_bf16(afrag, bfrag, acc[nt], 0, 0, 0);
        }
    }
#pragma unroll
    for (int nt = 0; nt < 8; nt++) {
        int col = n0 + nt * 16 + m16;
#pragma unroll
        for (int r = 0; r < 4; r++) {
            int row = m0 + wave * 16 + quad * 4 + r;
            if (row < N_NODES) C[(size_t)row * NHID + col] = f2bf(acc[nt][r]);
        }
    }
}

// ---------------- SpMM1 + bias + relu -> x1cat[:,256:512] (bf16) ----------------
__global__ __launch_bounds__(256) void spmm1_kernel(const int* __restrict__ offsets,
                                                    const int2* __restrict__ edges,
                                                    const unsigned short* __restrict__ S1b,
                                                    const float* __restrict__ b1,
                                                    unsigned short* __restrict__ x1cat) {
    int n = blockIdx.x * 4 + (threadIdx.x >> 6);
    int lane = threadIdx.x & 63;
    int beg = offsets[n], end = offsets[n + 1];
    float ax = 0.f, ay = 0.f, az = 0.f, aw = 0.f;
    int i = beg;
    for (; i + 4 <= end; i += 4) {
        int2 e0 = edges[i], e1 = edges[i + 1], e2 = edges[i + 2], e3 = edges[i + 3];
        float w0 = __builtin_bit_cast(float, e0.y);
        float w1 = __builtin_bit_cast(float, e1.y);
        float w2 = __builtin_bit_cast(float, e2.y);
        float w3 = __builtin_bit_cast(float, e3.y);
        ushort4v r0 = *(const ushort4v*)&S1b[(size_t)e0.x * NHID + lane * 4];
        ushort4v r1 = *(const ushort4v*)&S1b[(size_t)e1.x * NHID + lane * 4];
        ushort4v r2 = *(const ushort4v*)&S1b[(size_t)e2.x * NHID + lane * 4];
        ushort4v r3 = *(const ushort4v*)&S1b[(size_t)e3.x * NHID + lane * 4];
        ax += w0 * bf2f(r0[0]) + w1 * bf2f(r1[0]) + w2 * bf2f(r2[0]) + w3 * bf2f(r3[0]);
        ay += w0 * bf2f(r0[1]) + w1 * bf2f(r1[1]) + w2 * bf2f(r2[1]) + w3 * bf2f(r3[1]);
        az += w0 * bf2f(r0[2]) + w1 * bf2f(r1[2]) + w2 * bf2f(r2[2]) + w3 * bf2f(r3[2]);
        aw += w0 * bf2f(r0[3]) + w1 * bf2f(r1[3]) + w2 * bf2f(r2[3]) + w3 * bf2f(r3[3]);
    }
    for (; i < end; i++) {
        int2 e = edges[i];
        float ww = __builtin_bit_cast(float, e.y);
        ushort4v r = *(const ushort4v*)&S1b[(size_t)e.x * NHID + lane * 4];
        ax += ww * bf2f(r[0]); ay += ww * bf2f(r[1]);
        az += ww * bf2f(r[2]); aw += ww * bf2f(r[3]);
    }
    float4 bb = *(const float4*)&b1[lane * 4];
    ushort4v hb;
    hb[0] = f2bf(fmaxf(ax + bb.x, 0.f));
    hb[1] = f2bf(fmaxf(ay + bb.y, 0.f));
    hb[2] = f2bf(fmaxf(az + bb.z, 0.f));
    hb[3] = f2bf(fmaxf(aw + bb.w, 0.f));
    *(ushort4v*)&x1cat[(size_t)n * (2 * NHID) + NHID + lane * 4] = hb;
}

// ---------------- Fused MLP via MFMA: 16 nodes/block ----------------
__global__ __launch_bounds__(256) void mlp_mfma(const unsigned short* __restrict__ x1cat_ro,
                                                const float* __restrict__ eps,
                                                const float* __restrict__ b_mu,
                                                const float* __restrict__ b_lv,
                                                const unsigned short* __restrict__ W_mulvt,
                                                const float* __restrict__ b_dec,
                                                const unsigned short* __restrict__ W_dect,
                                                unsigned short* __restrict__ x1cat) {
    __shared__ float smulv[16][132];
    __shared__ unsigned short z_bf[16][72];
    int t = threadIdx.x;
    int wave = t >> 6, lane = t & 63;
    int quad = lane >> 4, m16 = lane & 15;
    int node0 = blockIdx.x * 16;

    // ---- phase A: mu||lv = h1 @ W_mulvt ----
    {
        floatx4 acc[2];
        acc[0] = (floatx4){0.f, 0.f, 0.f, 0.f};
        acc[1] = (floatx4){0.f, 0.f, 0.f, 0.f};
        const unsigned short* Abase =
            x1cat_ro + (size_t)(node0 + m16) * 512 + 256 + quad * 8;
        const unsigned short* Bb0 = W_mulvt + (size_t)(wave * 32 + m16) * 256 + quad * 8;
        const unsigned short* Bb1 = Bb0 + 16 * 256;
#pragma unroll
        for (int k0 = 0; k0 < 256; k0 += 32) {
            short8 afrag = *(const short8*)(Abase + k0);
            short8 bf0 = *(const short8*)(Bb0 + k0);
            short8 bf1 = *(const short8*)(Bb1 + k0);
            acc[0] = __builtin_amdgcn_mfma_f32_16x16x32_bf16(afrag, bf0, acc[0], 0, 0, 0);
            acc[1] = __builtin_amdgcn_mfma_f32_16x16x32_bf16(afrag, bf1, acc[1], 0, 0, 0);
        }
#pragma unroll
        for (int nt = 0; nt < 2; nt++) {
            int j = wave * 32 + nt * 16 + m16;
            float bias = (j < 64) ? b_mu[j] : b_lv[j - 64];
#pragma unroll
            for (int r = 0; r < 4; r++)
                smulv[quad * 4 + r][j] = acc[nt][r] + bias;
        }
    }
    __syncthreads();
    // ---- phase B: z = mu + eps*exp(lv) ----
#pragma unroll
    for (int r = 0; r < 4; r++) {
        int idx = t + r * 256;
        int n = idx >> 6, j = idx & 63;
        float z = smulv[n][j] + eps[(size_t)node0 * NCODE + idx] * expf(smulv[n][64 + j]);
        z_bf[n][j] = f2bf(z);
    }
    __syncthreads();
    // ---- phase C: x1 = relu(z @ W_dect + b_dec) ----
    {
        floatx4 acc[4];
#pragma unroll
        for (int i = 0; i < 4; i++) acc[i] = (floatx4){0.f, 0.f, 0.f, 0.f};
#pragma unroll
        for (int ks = 0; ks < 2; ks++) {
            int k0 = ks * 32;
            short8 afrag = *(const short8*)&z_bf[m16][k0 + quad * 8];
#pragma unroll
            for (int nt = 0; nt < 4; nt++) {
                int col = wave * 64 + nt * 16 + m16;
                short8 bfrag = *(const short8*)(W_dect + (size_t)col * 64 + k0 + quad * 8);
                acc[nt] = __builtin_amdgcn_mfma_f32_16x16x32_bf16(afrag, bfrag, acc[nt], 0, 0, 0);
            }
        }
#pragma unroll
        for (int nt = 0; nt < 4; nt++) {
            int col = wave * 64 + nt * 16 + m16;
            float bias = b_dec[col];
#pragma unroll
            for (int r = 0; r < 4; r++) {
                int node = node0 + quad * 4 + r;
                x1cat[(size_t)node * 512 + col] = f2bf(fmaxf(acc[nt][r] + bias, 0.f));
            }
        }
    }
}

// ---------------- GEMM2 (bf16 MFMA, LDS-staged, reg-prefetch): support2 = x1cat @ W2 ----------
__global__ __launch_bounds__(256) void gemm2_mfma(const unsigned short* __restrict__ Xb,
                                                  const unsigned short* __restrict__ Bt,
                                                  float* __restrict__ S2) {
    __shared__ unsigned short As[64][40];
    __shared__ unsigned short Bs[48][40];
    int t = threadIdx.x;
    int wave = t >> 6, lane = t & 63;
    int quad = lane >> 4, m16 = lane & 15;
    int m0 = blockIdx.x * 64;

    floatx4 acc[3];
#pragma unroll
    for (int i = 0; i < 3; i++) acc[i] = (floatx4){0.f, 0.f, 0.f, 0.f};

    int ar = t >> 2;
    int ako = (t & 3) * 8;
    int arow = m0 + ar;
    if (arow >= N_NODES) arow = N_NODES - 1;
    const unsigned short* Abase = Xb + (size_t)arow * NFEAT + ako;
    const unsigned short* Bbase = Bt + (size_t)(t >> 2) * NFEAT + ako;
    bool bload = (t >> 2) < NCLS_PAD;

    ushort8 a0 = *(const ushort8*)(Abase);
    ushort8 b0;
    if (bload) b0 = *(const ushort8*)(Bbase);

    for (int k0 = 0; k0 < NFEAT; k0 += 32) {
        __syncthreads();
        *(ushort8*)&As[ar][ako] = a0;
        if (bload) *(ushort8*)&Bs[t >> 2][ako] = b0;
        __syncthreads();
        int kn = (k0 + 32 < NFEAT) ? (k0 + 32) : k0;
        a0 = *(const ushort8*)(Abase + kn);
        if (bload) b0 = *(const ushort8*)(Bbase + kn);
        short8 afrag = *(const short8*)&As[wave * 16 + m16][quad * 8];
#pragma unroll
        for (int nt = 0; nt < 3; nt++) {
            short8 bfrag = *(const short8*)&Bs[nt * 16 + m16][quad * 8];
            acc[nt] = __builtin_amdgcn_mfma_f32_16x16x32_bf16(afrag, bfrag, acc[nt], 0, 0, 0);
        }
    }
#pragma unroll
    for (int nt = 0; nt < 3; nt++) {
        int col = nt * 16 + m16;
        if (col < NCLASS) {
#pragma unroll
            for (int r = 0; r < 4; r++) {
                int row = m0 + wave * 16 + quad * 4 + r;
                if (row < N_NODES) S2[(size_t)row * NCLASS + col] = acc[nt][r];
            }
        }
    }
}

// ---------------- SpMM2 + bias + log_softmax -> out ----------------
__global__ __launch_bounds__(256) void spmm2_softmax_kernel(const int* __restrict__ offsets,
                                                            const int2* __restrict__ edges,
                                                            const float* __restrict__ S2,
                                                            const float* __restrict__ b2,
                                                            float* __restrict__ out) {
    int wave = threadIdx.x >> 6;
    int lane = threadIdx.x & 63;
    int n = blockIdx.x * 4 + wave;
    int beg = offsets[n], end = offsets[n + 1];
    float acc = 0.f;
    int i = beg;
    for (; i + 4 <= end; i += 4) {
        int2 e0 = edges[i], e1 = edges[i + 1], e2 = edges[i + 2], e3 = edges[i + 3];
        float w0 = __builtin_bit_cast(float, e0.y);
        float w1 = __builtin_bit_cast(float, e1.y);
        float w2 = __builtin_bit_cast(float, e2.y);
        float w3 = __builtin_bit_cast(float, e3.y);
        if (lane < NCLASS) {
            float v0 = S2[(size_t)e0.x * NCLASS + lane];
            float v1 = S2[(size_t)e1.x * NCLASS + lane];
            float v2 = S2[(size_t)e2.x * NCLASS + lane];
            float v3 = S2[(size_t)e3.x * NCLASS + lane];
            acc += w0 * v0 + w1 * v1 + w2 * v2 + w3 * v3;
        }
    }
    for (; i < end; i++) {
        int2 e = edges[i];
        float ww = __builtin_bit_cast(float, e.y);
        if (lane < NCLASS) acc += ww * S2[(size_t)e.x * NCLASS + lane];
    }
    float v = (lane < NCLASS) ? (acc + b2[lane]) : -INFINITY;
    float m = v;
#pragma unroll
    for (int off = 32; off > 0; off >>= 1) m = fmaxf(m, __shfl_xor(m, off));
    float ex = (lane < NCLASS) ? expf(v - m) : 0.f;
    float ssum = ex;
#pragma unroll
    for (int off = 32; off > 0; off >>= 1) ssum += __shfl_xor(ssum, off);
    if (lane < NCLASS) out[(size_t)n * NCLASS + lane] = v - m - logf(ssum);
}

extern "C" void kernel_launch(void* const* d_in, const int* in_sizes, int n_in,
                              void* d_out, int out_size, void* d_ws, size_t ws_size,
                              hipStream_t stream) {
    const float* x     = (const float*)d_in[0];
    const int*   esrc  = (const int*)d_in[1];
    const int*   edst  = (const int*)d_in[2];
    const float* ew    = (const float*)d_in[3];
    const float* eps   = (const float*)d_in[4];
    const float* W1    = (const float*)d_in[5];
    const float* b1    = (const float*)d_in[6];
    const float* W_mu  = (const float*)d_in[7];
    const float* b_mu  = (const float*)d_in[8];
    const float* W_lv  = (const float*)d_in[9];
    const float* b_lv  = (const float*)d_in[10];
    const float* W_dec = (const float*)d_in[11];
    const float* b_dec = (const float*)d_in[12];
    const float* W2    = (const float*)d_in[13];
    const float* b2    = (const float*)d_in[14];
    float* out = (float*)d_out;

    // workspace layout (counts & cursor adjacent -> single memset)
    unsigned short* support1b = (unsigned short*)d_ws;                     // 12.8M u16
    unsigned short* x1cat = support1b + (size_t)N_NODES * NHID;            // 25.6M u16
    float* support2 = (float*)(x1cat + (size_t)N_NODES * 2 * NHID);        // 2M f32
    unsigned short* W1t    = (unsigned short*)(support2 + (size_t)N_NODES * NCLASS);
    unsigned short* W2bt   = W1t + (size_t)NHID * NFEAT;
    unsigned short* W_mulvt = W2bt + (size_t)NCLS_PAD * NFEAT;
    unsigned short* W_dect  = W_mulvt + 128 * 256;
    int*   counts   = (int*)(W_dect + 256 * 64);
    int*   cursor   = counts + N_NODES;
    int*   offsets  = cursor + N_NODES;     // N+1
    int*   blockSums    = offsets + N_NODES + 1;   // NB_SCAN
    int*   blockOffsets = blockSums + NB_SCAN;     // NB_SCAN
    int2*  edges    = (int2*)(blockOffsets + NB_SCAN);
    edges = (int2*)(((size_t)edges + 7) & ~(size_t)7);
    size_t need = (size_t)((char*)(edges + N_EDGES) - (char*)d_ws);
    if (ws_size < need) return;

    hipMemsetAsync(counts, 0, 2 * N_NODES * sizeof(int), stream);  // counts + cursor
    hist_kernel<<<(N_EDGES + 255) / 256, 256, 0, stream>>>(edst, counts);
    scan_block_sums<<<NB_SCAN, 256, 0, stream>>>(counts, blockSums);
    scan_block_offsets<<<1, 256, 0, stream>>>(blockSums, blockOffsets, offsets);
    scan_final<<<NB_SCAN, 256, 0, stream>>>(counts, blockOffsets, offsets);
    scatter_kernel<<<(N_EDGES + 255) / 256, 256, 0, stream>>>(edst, esrc, ew, offsets, cursor,
                                                              edges);

    wprep_kernel<<<800, 256, 0, stream>>>(W1, W2, W_mu, W_lv, W_dec, W1t, W2bt, W_mulvt, W_dect);
    dim3 g1((N_NODES + 63) / 64, 2);
    gemm1_mfma<<<g1, 256, 0, stream>>>(x, W1t, support1b);
    spmm1_kernel<<<N_NODES / 4, 256, 0, stream>>>(offsets, edges, support1b, b1, x1cat);
    mlp_mfma<<<N_NODES / 16, 256, 0, stream>>>(x1cat, eps, b_mu, b_lv, W_mulvt, b_dec, W_dect,
                                               x1cat);
    gemm2_mfma<<<(N_NODES + 63) / 64, 256, 0, stream>>>(x1cat, W2bt, support2);
    spmm2_softmax_kernel<<<N_NODES / 4, 256, 0, stream>>>(offsets, edges, support2, b2, out);
}

// Round 10
// 456.803 us; speedup vs baseline: 1.4211x; 1.0157x over previous
//
#include <hip/hip_runtime.h>
#include <math.h>

#define N_NODES 50000
#define N_EDGES 800000
#define NFEAT 512
#define NHID 256
#define NCODE 64
#define NCLASS 40
#define NCLS_PAD 48
#define NB_SCAN 196  // ceil(50000/256)

typedef __attribute__((ext_vector_type(8))) short short8;
typedef __attribute__((ext_vector_type(8))) unsigned short ushort8;
typedef __attribute__((ext_vector_type(4))) unsigned short ushort4v;
typedef __attribute__((ext_vector_type(4))) float floatx4;

__device__ inline unsigned short f2bf(float f) {
    unsigned u = __builtin_bit_cast(unsigned, f);
    u += 0x7fff + ((u >> 16) & 1);
    return (unsigned short)(u >> 16);
}
__device__ inline float bf2f(unsigned short h) {
    return __builtin_bit_cast(float, (unsigned)h << 16);
}

// ---------------- CSR build (by dst) ----------------
__global__ __launch_bounds__(256) void hist_kernel(const int* __restrict__ dst,
                                                   int* __restrict__ counts) {
    int t = blockIdx.x * 256 + threadIdx.x;
    if (t < N_EDGES) atomicAdd(&counts[dst[t]], 1);
}

// 3-phase device scan
__global__ __launch_bounds__(256) void scan_block_sums(const int* __restrict__ counts,
                                                       int* __restrict__ blockSums) {
    __shared__ int red[256];
    int t = threadIdx.x;
    int i = blockIdx.x * 256 + t;
    red[t] = (i < N_NODES) ? counts[i] : 0;
    __syncthreads();
#pragma unroll
    for (int off = 128; off > 0; off >>= 1) {
        if (t < off) red[t] += red[t + off];
        __syncthreads();
    }
    if (t == 0) blockSums[blockIdx.x] = red[0];
}

__global__ __launch_bounds__(256) void scan_block_offsets(const int* __restrict__ blockSums,
                                                          int* __restrict__ blockOffsets,
                                                          int* __restrict__ offsets) {
    __shared__ int s[256];
    int t = threadIdx.x;
    int v = (t < NB_SCAN) ? blockSums[t] : 0;
    s[t] = v;
    __syncthreads();
#pragma unroll
    for (int off = 1; off < 256; off <<= 1) {
        int x = (t >= off) ? s[t - off] : 0;
        __syncthreads();
        s[t] += x;
        __syncthreads();
    }
    if (t < NB_SCAN) blockOffsets[t] = s[t] - v;  // exclusive
    if (t == 255) offsets[N_NODES] = s[255];      // total = E
}

__global__ __launch_bounds__(256) void scan_final(const int* __restrict__ counts,
                                                  const int* __restrict__ blockOffsets,
                                                  int* __restrict__ offsets) {
    __shared__ int s[256];
    int t = threadIdx.x;
    int i = blockIdx.x * 256 + t;
    int v = (i < N_NODES) ? counts[i] : 0;
    s[t] = v;
    __syncthreads();
#pragma unroll
    for (int off = 1; off < 256; off <<= 1) {
        int x = (t >= off) ? s[t - off] : 0;
        __syncthreads();
        s[t] += x;
        __syncthreads();
    }
    if (i < N_NODES) offsets[i] = blockOffsets[blockIdx.x] + s[t] - v;  // exclusive
}

// scatter edges into dst-sorted order as packed (src, w_bits) int2
__global__ __launch_bounds__(256) void scatter_kernel(const int* __restrict__ dst,
                                                      const int* __restrict__ src,
                                                      const float* __restrict__ w,
                                                      const int* __restrict__ offsets,
                                                      int* __restrict__ cursor,
                                                      int2* __restrict__ edges) {
    int t = blockIdx.x * 256 + threadIdx.x;
    if (t < N_EDGES) {
        int d = dst[t];
        int pos = offsets[d] + atomicAdd(&cursor[d], 1);
        edges[pos] = make_int2(src[t], __builtin_bit_cast(int, w[t]));
    }
}

// ---------------- Fused weight prep: W1t / W2bt / W_mulvt / W_dect ----------------
__global__ __launch_bounds__(256) void wprep_kernel(const float* __restrict__ W1,
                                                    const float* __restrict__ W2,
                                                    const float* __restrict__ W_mu,
                                                    const float* __restrict__ W_lv,
                                                    const float* __restrict__ W_dec,
                                                    unsigned short* __restrict__ W1t,
                                                    unsigned short* __restrict__ W2bt,
                                                    unsigned short* __restrict__ W_mulvt,
                                                    unsigned short* __restrict__ W_dect) {
    int idx = blockIdx.x * 256 + threadIdx.x;
    if (idx < NFEAT * NHID) {
        int k = idx >> 8;
        int n = idx & 255;
        W1t[(size_t)n * NFEAT + k] = f2bf(W1[idx]);
    } else if (idx < NFEAT * NHID + NCLS_PAD * NFEAT) {
        int i2 = idx - NFEAT * NHID;
        int n = i2 >> 9;
        int k = i2 & 511;
        W2bt[i2] = (n < NCLASS) ? f2bf(W2[(size_t)k * NCLASS + n]) : (unsigned short)0;
    } else if (idx < NFEAT * NHID + NCLS_PAD * NFEAT + 128 * 256) {
        int i2 = idx - NFEAT * NHID - NCLS_PAD * NFEAT;
        int j = i2 >> 8;
        int k = i2 & 255;
        float v = (j < 64) ? W_mu[(size_t)k * NCODE + j] : W_lv[(size_t)k * NCODE + (j - 64)];
        W_mulvt[i2] = f2bf(v);
    } else if (idx < NFEAT * NHID + NCLS_PAD * NFEAT + 128 * 256 + 256 * 64) {
        int i2 = idx - NFEAT * NHID - NCLS_PAD * NFEAT - 128 * 256;
        int n = i2 >> 6;
        int k = i2 & 63;
        W_dect[i2] = f2bf(W_dec[(size_t)k * NHID + n]);
    }
}

// ---------------- GEMM1 (bf16 MFMA, 64x128 tile, BK=64): support1b = bf16(x @ W1) ------------
// BK=64: 128B/thread in flight per iter (2x MLP), 8 barriers instead of 16.
__global__ __launch_bounds__(256) void gemm1_mfma(const float* __restrict__ A,
                                                  const unsigned short* __restrict__ Bt,
                                                  unsigned short* __restrict__ C) {
    __shared__ unsigned short As[64][72];    // 9.2 KB  (pitch 72: conflict-spread)
    __shared__ unsigned short Bs[128][72];   // 18.4 KB
    int t = threadIdx.x;
    int wave = t >> 6, lane = t & 63;
    int quad = lane >> 4, m16 = lane & 15;
    int m0 = blockIdx.x * 64;
    int n0 = blockIdx.y * 128;

    floatx4 acc[8];
#pragma unroll
    for (int i = 0; i < 8; i++) acc[i] = (floatx4){0.f, 0.f, 0.f, 0.f};

    int ar = t >> 2;            // 0..63 A row
    int ako = (t & 3) * 16;     // 0,16,32,48
    int arow = m0 + ar;
    if (arow >= N_NODES) arow = N_NODES - 1;
    const float* Abase = A + (size_t)arow * NFEAT + ako;

    int bcol = t >> 1;          // 0..127 local col
    int bko = (t & 1) * 32;     // 0 or 32
    const unsigned short* Bbase = Bt + (size_t)(n0 + bcol) * NFEAT + bko;

    for (int k0 = 0; k0 < NFEAT; k0 += 64) {
        float4 a0 = *(const float4*)(Abase + k0);
        float4 a1 = *(const float4*)(Abase + k0 + 4);
        float4 a2 = *(const float4*)(Abase + k0 + 8);
        float4 a3 = *(const float4*)(Abase + k0 + 12);
        ushort8 b0 = *(const ushort8*)(Bbase + k0);
        ushort8 b1 = *(const ushort8*)(Bbase + k0 + 8);
        ushort8 b2 = *(const ushort8*)(Bbase + k0 + 16);
        ushort8 b3 = *(const ushort8*)(Bbase + k0 + 24);
        __syncthreads();
        ushort8 av0, av1;
        av0[0] = f2bf(a0.x); av0[1] = f2bf(a0.y); av0[2] = f2bf(a0.z); av0[3] = f2bf(a0.w);
        av0[4] = f2bf(a1.x); av0[5] = f2bf(a1.y); av0[6] = f2bf(a1.z); av0[7] = f2bf(a1.w);
        av1[0] = f2bf(a2.x); av1[1] = f2bf(a2.y); av1[2] = f2bf(a2.z); av1[3] = f2bf(a2.w);
        av1[4] = f2bf(a3.x); av1[5] = f2bf(a3.y); av1[6] = f2bf(a3.z); av1[7] = f2bf(a3.w);
        *(ushort8*)&As[ar][ako] = av0;
        *(ushort8*)&As[ar][ako + 8] = av1;
        *(ushort8*)&Bs[bcol][bko] = b0;
        *(ushort8*)&Bs[bcol][bko + 8] = b1;
        *(ushort8*)&Bs[bcol][bko + 16] = b2;
        *(ushort8*)&Bs[bcol][bko + 24] = b3;
        __syncthreads();
#pragma unroll
        for (int c = 0; c < 2; c++) {
            short8 afrag = *(const short8*)&As[wave * 16 + m16][c * 32 + quad * 8];
#pragma unroll
            for (int nt = 0; nt < 8; nt++) {
                short8 bfrag = *(const short8*)&Bs[nt * 16 + m16][c * 32 + quad * 8];
                acc[nt] = __builtin_amdgcn_mfma_f32_16x16x32_bf16(afrag, bfrag, acc[nt], 0, 0, 0);
            }
        }
    }
#pragma unroll
    for (int nt = 0; nt < 8; nt++) {
        int col = n0 + nt * 16 + m16;
#pragma unroll
        for (int r = 0; r < 4; r++) {
            int row = m0 + wave * 16 + quad * 4 + r;
            if (row < N_NODES) C[(size_t)row * NHID + col] = f2bf(acc[nt][r]);
        }
    }
}

// ---------------- SpMM1 + bias + relu -> x1cat[:,256:512] (bf16) ----------------
__global__ __launch_bounds__(256) void spmm1_kernel(const int* __restrict__ offsets,
                                                    const int2* __restrict__ edges,
                                                    const unsigned short* __restrict__ S1b,
                                                    const float* __restrict__ b1,
                                                    unsigned short* __restrict__ x1cat) {
    int n = blockIdx.x * 4 + (threadIdx.x >> 6);
    int lane = threadIdx.x & 63;
    int beg = offsets[n], end = offsets[n + 1];
    float ax = 0.f, ay = 0.f, az = 0.f, aw = 0.f;
    int i = beg;
    for (; i + 4 <= end; i += 4) {
        int2 e0 = edges[i], e1 = edges[i + 1], e2 = edges[i + 2], e3 = edges[i + 3];
        float w0 = __builtin_bit_cast(float, e0.y);
        float w1 = __builtin_bit_cast(float, e1.y);
        float w2 = __builtin_bit_cast(float, e2.y);
        float w3 = __builtin_bit_cast(float, e3.y);
        ushort4v r0 = *(const ushort4v*)&S1b[(size_t)e0.x * NHID + lane * 4];
        ushort4v r1 = *(const ushort4v*)&S1b[(size_t)e1.x * NHID + lane * 4];
        ushort4v r2 = *(const ushort4v*)&S1b[(size_t)e2.x * NHID + lane * 4];
        ushort4v r3 = *(const ushort4v*)&S1b[(size_t)e3.x * NHID + lane * 4];
        ax += w0 * bf2f(r0[0]) + w1 * bf2f(r1[0]) + w2 * bf2f(r2[0]) + w3 * bf2f(r3[0]);
        ay += w0 * bf2f(r0[1]) + w1 * bf2f(r1[1]) + w2 * bf2f(r2[1]) + w3 * bf2f(r3[1]);
        az += w0 * bf2f(r0[2]) + w1 * bf2f(r1[2]) + w2 * bf2f(r2[2]) + w3 * bf2f(r3[2]);
        aw += w0 * bf2f(r0[3]) + w1 * bf2f(r1[3]) + w2 * bf2f(r2[3]) + w3 * bf2f(r3[3]);
    }
    for (; i < end; i++) {
        int2 e = edges[i];
        float ww = __builtin_bit_cast(float, e.y);
        ushort4v r = *(const ushort4v*)&S1b[(size_t)e.x * NHID + lane * 4];
        ax += ww * bf2f(r[0]); ay += ww * bf2f(r[1]);
        az += ww * bf2f(r[2]); aw += ww * bf2f(r[3]);
    }
    float4 bb = *(const float4*)&b1[lane * 4];
    ushort4v hb;
    hb[0] = f2bf(fmaxf(ax + bb.x, 0.f));
    hb[1] = f2bf(fmaxf(ay + bb.y, 0.f));
    hb[2] = f2bf(fmaxf(az + bb.z, 0.f));
    hb[3] = f2bf(fmaxf(aw + bb.w, 0.f));
    *(ushort4v*)&x1cat[(size_t)n * (2 * NHID) + NHID + lane * 4] = hb;
}

// ---------------- Fused MLP via MFMA: 16 nodes/block ----------------
__global__ __launch_bounds__(256) void mlp_mfma(const unsigned short* __restrict__ x1cat_ro,
                                                const float* __restrict__ eps,
                                                const float* __restrict__ b_mu,
                                                const float* __restrict__ b_lv,
                                                const unsigned short* __restrict__ W_mulvt,
                                                const float* __restrict__ b_dec,
                                                const unsigned short* __restrict__ W_dect,
                                                unsigned short* __restrict__ x1cat) {
    __shared__ float smulv[16][132];
    __shared__ unsigned short z_bf[16][72];
    int t = threadIdx.x;
    int wave = t >> 6, lane = t & 63;
    int quad = lane >> 4, m16 = lane & 15;
    int node0 = blockIdx.x * 16;

    // ---- phase A: mu||lv = h1 @ W_mulvt ----
    {
        floatx4 acc[2];
        acc[0] = (floatx4){0.f, 0.f, 0.f, 0.f};
        acc[1] = (floatx4){0.f, 0.f, 0.f, 0.f};
        const unsigned short* Abase =
            x1cat_ro + (size_t)(node0 + m16) * 512 + 256 + quad * 8;
        const unsigned short* Bb0 = W_mulvt + (size_t)(wave * 32 + m16) * 256 + quad * 8;
        const unsigned short* Bb1 = Bb0 + 16 * 256;
#pragma unroll
        for (int k0 = 0; k0 < 256; k0 += 32) {
            short8 afrag = *(const short8*)(Abase + k0);
            short8 bf0 = *(const short8*)(Bb0 + k0);
            short8 bf1 = *(const short8*)(Bb1 + k0);
            acc[0] = __builtin_amdgcn_mfma_f32_16x16x32_bf16(afrag, bf0, acc[0], 0, 0, 0);
            acc[1] = __builtin_amdgcn_mfma_f32_16x16x32_bf16(afrag, bf1, acc[1], 0, 0, 0);
        }
#pragma unroll
        for (int nt = 0; nt < 2; nt++) {
            int j = wave * 32 + nt * 16 + m16;
            float bias = (j < 64) ? b_mu[j] : b_lv[j - 64];
#pragma unroll
            for (int r = 0; r < 4; r++)
                smulv[quad * 4 + r][j] = acc[nt][r] + bias;
        }
    }
    __syncthreads();
    // ---- phase B: z = mu + eps*exp(lv) ----
#pragma unroll
    for (int r = 0; r < 4; r++) {
        int idx = t + r * 256;
        int n = idx >> 6, j = idx & 63;
        float z = smulv[n][j] + eps[(size_t)node0 * NCODE + idx] * expf(smulv[n][64 + j]);
        z_bf[n][j] = f2bf(z);
    }
    __syncthreads();
    // ---- phase C: x1 = relu(z @ W_dect + b_dec) ----
    {
        floatx4 acc[4];
#pragma unroll
        for (int i = 0; i < 4; i++) acc[i] = (floatx4){0.f, 0.f, 0.f, 0.f};
#pragma unroll
        for (int ks = 0; ks < 2; ks++) {
            int k0 = ks * 32;
            short8 afrag = *(const short8*)&z_bf[m16][k0 + quad * 8];
#pragma unroll
            for (int nt = 0; nt < 4; nt++) {
                int col = wave * 64 + nt * 16 + m16;
                short8 bfrag = *(const short8*)(W_dect + (size_t)col * 64 + k0 + quad * 8);
                acc[nt] = __builtin_amdgcn_mfma_f32_16x16x32_bf16(afrag, bfrag, acc[nt], 0, 0, 0);
            }
        }
#pragma unroll
        for (int nt = 0; nt < 4; nt++) {
            int col = wave * 64 + nt * 16 + m16;
            float bias = b_dec[col];
#pragma unroll
            for (int r = 0; r < 4; r++) {
                int node = node0 + quad * 4 + r;
                x1cat[(size_t)node * 512 + col] = f2bf(fmaxf(acc[nt][r] + bias, 0.f));
            }
        }
    }
}

// ---------------- GEMM2 (bf16 MFMA, LDS-staged, reg-prefetch): support2 = x1cat @ W2 ----------
__global__ __launch_bounds__(256) void gemm2_mfma(const unsigned short* __restrict__ Xb,
                                                  const unsigned short* __restrict__ Bt,
                                                  float* __restrict__ S2) {
    __shared__ unsigned short As[64][40];
    __shared__ unsigned short Bs[48][40];
    int t = threadIdx.x;
    int wave = t >> 6, lane = t & 63;
    int quad = lane >> 4, m16 = lane & 15;
    int m0 = blockIdx.x * 64;

    floatx4 acc[3];
#pragma unroll
    for (int i = 0; i < 3; i++) acc[i] = (floatx4){0.f, 0.f, 0.f, 0.f};

    int ar = t >> 2;
    int ako = (t & 3) * 8;
    int arow = m0 + ar;
    if (arow >= N_NODES) arow = N_NODES - 1;
    const unsigned short* Abase = Xb + (size_t)arow * NFEAT + ako;
    const unsigned short* Bbase = Bt + (size_t)(t >> 2) * NFEAT + ako;
    bool bload = (t >> 2) < NCLS_PAD;

    ushort8 a0 = *(const ushort8*)(Abase);
    ushort8 b0;
    if (bload) b0 = *(const ushort8*)(Bbase);

    for (int k0 = 0; k0 < NFEAT; k0 += 32) {
        __syncthreads();
        *(ushort8*)&As[ar][ako] = a0;
        if (bload) *(ushort8*)&Bs[t >> 2][ako] = b0;
        __syncthreads();
        int kn = (k0 + 32 < NFEAT) ? (k0 + 32) : k0;
        a0 = *(const ushort8*)(Abase + kn);
        if (bload) b0 = *(const ushort8*)(Bbase + kn);
        short8 afrag = *(const short8*)&As[wave * 16 + m16][quad * 8];
#pragma unroll
        for (int nt = 0; nt < 3; nt++) {
            short8 bfrag = *(const short8*)&Bs[nt * 16 + m16][quad * 8];
            acc[nt] = __builtin_amdgcn_mfma_f32_16x16x32_bf16(afrag, bfrag, acc[nt], 0, 0, 0);
        }
    }
#pragma unroll
    for (int nt = 0; nt < 3; nt++) {
        int col = nt * 16 + m16;
        if (col < NCLASS) {
#pragma unroll
            for (int r = 0; r < 4; r++) {
                int row = m0 + wave * 16 + quad * 4 + r;
                if (row < N_NODES) S2[(size_t)row * NCLASS + col] = acc[nt][r];
            }
        }
    }
}

// ---------------- SpMM2 + bias + log_softmax -> out ----------------
__global__ __launch_bounds__(256) void spmm2_softmax_kernel(const int* __restrict__ offsets,
                                                            const int2* __restrict__ edges,
                                                            const float* __restrict__ S2,
                                                            const float* __restrict__ b2,
                                                            float* __restrict__ out) {
    int wave = threadIdx.x >> 6;
    int lane = threadIdx.x & 63;
    int n = blockIdx.x * 4 + wave;
    int beg = offsets[n], end = offsets[n + 1];
    float acc = 0.f;
    int i = beg;
    for (; i + 4 <= end; i += 4) {
        int2 e0 = edges[i], e1 = edges[i + 1], e2 = edges[i + 2], e3 = edges[i + 3];
        float w0 = __builtin_bit_cast(float, e0.y);
        float w1 = __builtin_bit_cast(float, e1.y);
        float w2 = __builtin_bit_cast(float, e2.y);
        float w3 = __builtin_bit_cast(float, e3.y);
        if (lane < NCLASS) {
            float v0 = S2[(size_t)e0.x * NCLASS + lane];
            float v1 = S2[(size_t)e1.x * NCLASS + lane];
            float v2 = S2[(size_t)e2.x * NCLASS + lane];
            float v3 = S2[(size_t)e3.x * NCLASS + lane];
            acc += w0 * v0 + w1 * v1 + w2 * v2 + w3 * v3;
        }
    }
    for (; i < end; i++) {
        int2 e = edges[i];
        float ww = __builtin_bit_cast(float, e.y);
        if (lane < NCLASS) acc += ww * S2[(size_t)e.x * NCLASS + lane];
    }
    float v = (lane < NCLASS) ? (acc + b2[lane]) : -INFINITY;
    float m = v;
#pragma unroll
    for (int off = 32; off > 0; off >>= 1) m = fmaxf(m, __shfl_xor(m, off));
    float ex = (lane < NCLASS) ? expf(v - m) : 0.f;
    float ssum = ex;
#pragma unroll
    for (int off = 32; off > 0; off >>= 1) ssum += __shfl_xor(ssum, off);
    if (lane < NCLASS) out[(size_t)n * NCLASS + lane] = v - m - logf(ssum);
}

extern "C" void kernel_launch(void* const* d_in, const int* in_sizes, int n_in,
                              void* d_out, int out_size, void* d_ws, size_t ws_size,
                              hipStream_t stream) {
    const float* x     = (const float*)d_in[0];
    const int*   esrc  = (const int*)d_in[1];
    const int*   edst  = (const int*)d_in[2];
    const float* ew    = (const float*)d_in[3];
    const float* eps   = (const float*)d_in[4];
    const float* W1    = (const float*)d_in[5];
    const float* b1    = (const float*)d_in[6];
    const float* W_mu  = (const float*)d_in[7];
    const float* b_mu  = (const float*)d_in[8];
    const float* W_lv  = (const float*)d_in[9];
    const float* b_lv  = (const float*)d_in[10];
    const float* W_dec = (const float*)d_in[11];
    const float* b_dec = (const float*)d_in[12];
    const float* W2    = (const float*)d_in[13];
    const float* b2    = (const float*)d_in[14];
    float* out = (float*)d_out;

    // workspace layout (counts & cursor adjacent -> single memset)
    unsigned short* support1b = (unsigned short*)d_ws;                     // 12.8M u16
    unsigned short* x1cat = support1b + (size_t)N_NODES * NHID;            // 25.6M u16
    float* support2 = (float*)(x1cat + (size_t)N_NODES * 2 * NHID);        // 2M f32
    unsigned short* W1t    = (unsigned short*)(support2 + (size_t)N_NODES * NCLASS);
    unsigned short* W2bt   = W1t + (size_t)NHID * NFEAT;
    unsigned short* W_mulvt = W2bt + (size_t)NCLS_PAD * NFEAT;
    unsigned short* W_dect  = W_mulvt + 128 * 256;
    int*   counts   = (int*)(W_dect + 256 * 64);
    int*   cursor   = counts + N_NODES;
    int*   offsets  = cursor + N_NODES;     // N+1
    int*   blockSums    = offsets + N_NODES + 1;   // NB_SCAN
    int*   blockOffsets = blockSums + NB_SCAN;     // NB_SCAN
    int2*  edges    = (int2*)(blockOffsets + NB_SCAN);
    edges = (int2*)(((size_t)edges + 7) & ~(size_t)7);
    size_t need = (size_t)((char*)(edges + N_EDGES) - (char*)d_ws);
    if (ws_size < need) return;

    hipMemsetAsync(counts, 0, 2 * N_NODES * sizeof(int), stream);  // counts + cursor
    hist_kernel<<<(N_EDGES + 255) / 256, 256, 0, stream>>>(edst, counts);
    scan_block_sums<<<NB_SCAN, 256, 0, stream>>>(counts, blockSums);
    scan_block_offsets<<<1, 256, 0, stream>>>(blockSums, blockOffsets, offsets);
    scan_final<<<NB_SCAN, 256, 0, stream>>>(counts, blockOffsets, offsets);
    scatter_kernel<<<(N_EDGES + 255) / 256, 256, 0, stream>>>(edst, esrc, ew, offsets, cursor,
                                                              edges);

    wprep_kernel<<<800, 256, 0, stream>>>(W1, W2, W_mu, W_lv, W_dec, W1t, W2bt, W_mulvt, W_dect);
    dim3 g1((N_NODES + 63) / 64, 2);
    gemm1_mfma<<<g1, 256, 0, stream>>>(x, W1t, support1b);
    spmm1_kernel<<<N_NODES / 4, 256, 0, stream>>>(offsets, edges, support1b, b1, x1cat);
    mlp_mfma<<<N_NODES / 16, 256, 0, stream>>>(x1cat, eps, b_mu, b_lv, W_mulvt, b_dec, W_dect,
                                               x1cat);
    gemm2_mfma<<<(N_NODES + 63) / 64, 256, 0, stream>>>(x1cat, W2bt, support2);
    spmm2_softmax_kernel<<<N_NODES / 4, 256, 0, stream>>>(offsets, edges, support2, b2, out);
}